// Round 1
// baseline (85.038 us; speedup 1.0000x reference)
//
#include <hip/hip_runtime.h>

// Problem constants (from reference): B=4, N=512, D=256, H=256, M = B*N = 2048
// out[b,i,j] = 0.5*(E + E^T),  E[b,i,j] = sum_h v[h]*tanh(Q[b,i,h]+K[b,j,h])
// tanh(q+k) = 1 - 2/(1 + e^{2q} e^{2k});  u = exp2(C2*q), w = exp2(C2*k), C2 = 2*log2(e)
// E_ij = S_v - 2*acc_ij, acc_ij = sum_h v_h / (1 + u_ih w_jh)
// out_ij = S_v - (acc_ij + acc_ji)

typedef float f4 __attribute__((ext_vector_type(4)));
typedef float f32x4 __attribute__((ext_vector_type(4)));
typedef __bf16 bf16x8 __attribute__((ext_vector_type(8)));

#define C2F 2.8853900817779268f

__device__ inline unsigned short f2bf(float f) {
    unsigned u = __float_as_uint(f);
    unsigned r = (u + 0x7fffu + ((u >> 16) & 1u)) >> 16;
    return (unsigned short)r;
}
__device__ inline float bf2f(unsigned short h) {
    return __uint_as_float(((unsigned)h) << 16);
}

__device__ inline void split_store(const f4 a0, const f4 a1,
                                   unsigned short* hip, unsigned short* lop) {
    float f[8];
    unsigned short h[8], l[8];
#pragma unroll
    for (int t = 0; t < 4; ++t) { f[t] = a0[t]; f[t + 4] = a1[t]; }
#pragma unroll
    for (int t = 0; t < 8; ++t) {
        h[t] = f2bf(f[t]);
        l[t] = f2bf(f[t] - bf2f(h[t]));
    }
    uint4 hv, lv;
    hv.x = (unsigned)h[0] | ((unsigned)h[1] << 16);
    hv.y = (unsigned)h[2] | ((unsigned)h[3] << 16);
    hv.z = (unsigned)h[4] | ((unsigned)h[5] << 16);
    hv.w = (unsigned)h[6] | ((unsigned)h[7] << 16);
    lv.x = (unsigned)l[0] | ((unsigned)l[1] << 16);
    lv.y = (unsigned)l[2] | ((unsigned)l[3] << 16);
    lv.z = (unsigned)l[4] | ((unsigned)l[5] << 16);
    lv.w = (unsigned)l[6] | ((unsigned)l[7] << 16);
    *(uint4*)hip = hv;
    *(uint4*)lop = lv;
}

// C[m, n] = act( sum_k A[m,k] * Wsel[n,k] + bias[n] )
// Wsel row n: n<256 -> Wa[n], else Wb[n-256].  ACT: 0=none, 1=tanh, 2=exp2(C2*x)
// A: [2048 x 256] fp32. Split-bf16 MFMA (hi+lo), fp32 accumulate.
template <int ACT>
__global__ __launch_bounds__(256) void gemm_split(
    const float* __restrict__ A, const float* __restrict__ Wa,
    const float* __restrict__ Wb, const float* __restrict__ ba,
    const float* __restrict__ bb2, float* __restrict__ C, int Nn) {
    __shared__ unsigned short sAhi[64][40];
    __shared__ unsigned short sAlo[64][40];
    __shared__ unsigned short sBhi[64][40];
    __shared__ unsigned short sBlo[64][40];

    const int tid = threadIdx.x;
    const int m0 = blockIdx.x << 6;
    const int n0 = blockIdx.y << 6;
    const int lane = tid & 63;
    const int wv = tid >> 6;
    const int wm = wv >> 1, wn = wv & 1;
    const int fr = lane & 15;
    const int fks = (lane >> 4) << 3;  // 0,8,16,24

    f32x4 acc[2][2];
#pragma unroll
    for (int i = 0; i < 2; ++i)
#pragma unroll
        for (int j = 0; j < 2; ++j) acc[i][j] = (f32x4){0.f, 0.f, 0.f, 0.f};

    const int srow = tid >> 2;          // 0..63
    const int scol8 = (tid & 3) << 3;   // 0,8,16,24

    const float* Arow = &A[(size_t)(m0 + srow) * 256 + scol8];
    const int wrow = n0 + srow;
    const float* Wrow = (wrow < 256) ? &Wa[(size_t)wrow * 256 + scol8]
                                     : &Wb[(size_t)(wrow - 256) * 256 + scol8];

    for (int kt = 0; kt < 256; kt += 32) {
        f4 a0 = *(const f4*)(Arow + kt);
        f4 a1 = *(const f4*)(Arow + kt + 4);
        f4 w0 = *(const f4*)(Wrow + kt);
        f4 w1 = *(const f4*)(Wrow + kt + 4);
        split_store(a0, a1, &sAhi[srow][scol8], &sAlo[srow][scol8]);
        split_store(w0, w1, &sBhi[srow][scol8], &sBlo[srow][scol8]);
        __syncthreads();

        bf16x8 ah[2], al[2], bh[2], bl[2];
#pragma unroll
        for (int s = 0; s < 2; ++s) {
            ah[s] = *(const bf16x8*)&sAhi[(wm << 5) + (s << 4) + fr][fks];
            al[s] = *(const bf16x8*)&sAlo[(wm << 5) + (s << 4) + fr][fks];
            bh[s] = *(const bf16x8*)&sBhi[(wn << 5) + (s << 4) + fr][fks];
            bl[s] = *(const bf16x8*)&sBlo[(wn << 5) + (s << 4) + fr][fks];
        }
#pragma unroll
        for (int i = 0; i < 2; ++i)
#pragma unroll
            for (int j = 0; j < 2; ++j) {
                acc[i][j] = __builtin_amdgcn_mfma_f32_16x16x32_bf16(ah[i], bh[j], acc[i][j], 0, 0, 0);
                acc[i][j] = __builtin_amdgcn_mfma_f32_16x16x32_bf16(ah[i], bl[j], acc[i][j], 0, 0, 0);
                acc[i][j] = __builtin_amdgcn_mfma_f32_16x16x32_bf16(al[i], bh[j], acc[i][j], 0, 0, 0);
            }
        __syncthreads();
    }

    // epilogue: D[row=(lane>>4)*4+q][col=lane&15] per 16x16 fragment
    const int rbase = (lane >> 4) << 2;
#pragma unroll
    for (int i = 0; i < 2; ++i) {
#pragma unroll
        for (int j = 0; j < 2; ++j) {
            const int gcol = n0 + (wn << 5) + (j << 4) + fr;
            const float bias = (ACT == 2 && gcol >= 256) ? bb2[gcol - 256] : ba[gcol];
#pragma unroll
            for (int q = 0; q < 4; ++q) {
                const int grow = m0 + (wm << 5) + (i << 4) + rbase + q;
                float x = acc[i][j][q] + bias;
                if (ACT == 1)
                    x = 1.0f - 2.0f * __builtin_amdgcn_rcpf(
                                          1.0f + __builtin_amdgcn_exp2f(C2F * x));
                if (ACT == 2) x = __builtin_amdgcn_exp2f(C2F * x);
                C[(size_t)grow * Nn + gcol] = x;
            }
        }
    }
}

// Pairwise: Ep[b,i,j] = sum_h v_h * rcp(1 + u[b,i,h]*w[b,j,h])
// uwb: [2048 x 512]; u = cols [0,256), w = cols [256,512)
__global__ __launch_bounds__(256) void pairwise_kernel(
    const float* __restrict__ uwb, const float* __restrict__ v,
    float* __restrict__ Ep) {
    __shared__ float sU[64][260];
    __shared__ float sW[64][260];
    __shared__ float sV[256];

    const int tid = threadIdx.x;
    const int lane = tid & 63, wv = tid >> 6;
    const int bb = blockIdx.x;
    const int b = bb >> 6;
    const int i0 = ((bb >> 3) & 7) << 6;
    const int j0 = (bb & 7) << 6;

    // stage u rows [i0,i0+64) and w rows [j0,j0+64) into LDS (padded rows)
#pragma unroll 8
    for (int kk = 0; kk < 32; ++kk) {
        const int g = (kk << 2) + wv;  // wave-uniform
        const float* src;
        float* dst;
        if (g < 64) {
            src = &uwb[(size_t)((b << 9) + i0 + g) * 512];
            dst = &sU[g][0];
        } else {
            src = &uwb[(size_t)((b << 9) + j0 + (g - 64)) * 512 + 256];
            dst = &sW[g - 64][0];
        }
        *(f4*)(dst + (lane << 2)) = *(const f4*)(src + (lane << 2));
    }
    if (tid < 64) *(f4*)&sV[tid << 2] = *(const f4*)&v[tid << 2];
    __syncthreads();

    const int ty = tid >> 4, tx = tid & 15;
    float acc[4][4];
#pragma unroll
    for (int i = 0; i < 4; ++i)
#pragma unroll
        for (int j = 0; j < 4; ++j) acc[i][j] = 0.f;

    f4 uuA[4], wwA[4], vvA, uuB[4], wwB[4], vvB;

#define LOADSTEP(S, hh)                                       \
    {                                                         \
        vv##S = *(const f4*)&sV[hh];                          \
        _Pragma("unroll") for (int d = 0; d < 4; ++d) {       \
            uu##S[d] = *(const f4*)&sU[ty + (d << 4)][hh];    \
            ww##S[d] = *(const f4*)&sW[tx + (d << 4)][hh];    \
        }                                                     \
    }
#define COMPUTE(S)                                                         \
    {                                                                      \
        _Pragma("unroll") for (int t = 0; t < 4; ++t)                      \
        _Pragma("unroll") for (int i = 0; i < 4; ++i)                      \
        _Pragma("unroll") for (int j = 0; j < 4; ++j) {                    \
            float dnm = fmaf(uu##S[i][t], ww##S[j][t], 1.0f);              \
            acc[i][j] = fmaf(vv##S[t], __builtin_amdgcn_rcpf(dnm), acc[i][j]); \
        }                                                                  \
    }

    LOADSTEP(A, 0)
    for (int h = 0; h < 256; h += 8) {
        LOADSTEP(B, h + 4)
        COMPUTE(A)
        if (h + 8 < 256) LOADSTEP(A, h + 8)
        COMPUTE(B)
    }
#undef LOADSTEP
#undef COMPUTE

#pragma unroll
    for (int i = 0; i < 4; ++i)
#pragma unroll
        for (int j = 0; j < 4; ++j)
            Ep[(size_t)((b << 9) + i0 + ty + (i << 4)) * 512 + j0 + tx + (j << 4)] =
                acc[i][j];
}

// out[b,i,j] = S_v - (Ep[b,i,j] + Ep[b,j,i])
__global__ __launch_bounds__(256) void sym_kernel(const float* __restrict__ Ep,
                                                  const float* __restrict__ v,
                                                  float* __restrict__ out) {
    __shared__ float t1[64][65];
    __shared__ float t2[64][65];
    __shared__ float red[4];

    const int tid = threadIdx.x;
    const int lane = tid & 63, wv = tid >> 6;

    float x = v[tid];
#pragma unroll
    for (int o = 32; o > 0; o >>= 1) x += __shfl_xor(x, o, 64);
    if (lane == 0) red[wv] = x;

    const int bb = blockIdx.x;
    const int b = bb >> 6;
    const int i0 = ((bb >> 3) & 7) << 6;
    const int j0 = (bb & 7) << 6;

    for (int idx = tid; idx < 4096; idx += 256) {
        const int r = idx >> 6, c = idx & 63;
        t1[r][c] = Ep[(size_t)((b << 9) + i0 + r) * 512 + j0 + c];
        t2[r][c] = Ep[(size_t)((b << 9) + j0 + r) * 512 + i0 + c];
    }
    __syncthreads();
    const float Sv = red[0] + red[1] + red[2] + red[3];
    for (int idx = tid; idx < 4096; idx += 256) {
        const int r = idx >> 6, c = idx & 63;
        out[(size_t)((b << 9) + i0 + r) * 512 + j0 + c] = Sv - (t1[r][c] + t2[c][r]);
    }
}

extern "C" void kernel_launch(void* const* d_in, const int* in_sizes, int n_in,
                              void* d_out, int out_size, void* d_ws, size_t ws_size,
                              hipStream_t stream) {
    const float* X  = (const float*)d_in[0];
    // d_in[1] = Y (unused by reference)
    const float* W1 = (const float*)d_in[2];
    const float* b1 = (const float*)d_in[3];
    const float* W2 = (const float*)d_in[4];
    const float* b2 = (const float*)d_in[5];
    const float* Wq = (const float*)d_in[6];
    const float* bq = (const float*)d_in[7];
    const float* Wk = (const float*)d_in[8];
    const float* bk = (const float*)d_in[9];
    const float* v  = (const float*)d_in[10];
    // d_in[11] = k (unused by reference)

    float* ws  = (float*)d_ws;
    float* h1  = ws;                 // 2048*256 = 524288 floats (2 MB)
    float* h2  = ws + 524288;        // 2 MB
    float* uwb = ws + 1048576;       // 2048*512 = 1048576 floats (4 MB)
    float* Ep  = ws + 2097152;       // 4*512*512 = 1048576 floats (4 MB)
    float* out = (float*)d_out;

    // h1 = tanh(X @ W1^T + b1)
    gemm_split<1><<<dim3(32, 4), 256, 0, stream>>>(X, W1, W1, b1, b1, h1, 256);
    // h2 = h1 @ W2^T + b2
    gemm_split<0><<<dim3(32, 4), 256, 0, stream>>>(h1, W2, W2, b2, b2, h2, 256);
    // uw[:, :256] = exp2(C2*(h2@Wq^T+bq)), uw[:, 256:] = exp2(C2*(h2@Wk^T+bk))
    gemm_split<2><<<dim3(32, 8), 256, 0, stream>>>(h2, Wq, Wk, bq, bk, uwb, 512);
    // Ep[b,i,j] = sum_h v_h * rcp(1 + u*w)
    pairwise_kernel<<<256, 256, 0, stream>>>(uwb, v, Ep);
    // out = S_v - (Ep + Ep^T)
    sym_kernel<<<256, 256, 0, stream>>>(Ep, v, out);
}

// Round 2
// 76.334 us; speedup vs baseline: 1.1140x; 1.1140x over previous
//
#include <hip/hip_runtime.h>

// Problem: B=4, N=512, D=256, H=256, M = B*N = 2048
// out[b,i,j] = 0.5*(E + E^T),  E[b,i,j] = sum_h v[h]*tanh(Q[b,i,h]+K[b,j,h])
// tanh(q+k) = 1 - 2/(1 + e^{2q} e^{2k});  u = exp2(C2*q), w = exp2(C2*k), C2 = 2*log2(e)
// acc_ij = sum_h v_h / (1 + u_ih w_jh);  out_ij = S_v - (acc_ij + acc_ji)
// Algebraic fold: no activation between fc2 and Q/K proj:
//   Q = h1 @ (Wq@W2)^T + (Wq@b2 + bq)   (same for K)

typedef float f2 __attribute__((ext_vector_type(2)));
typedef float f4 __attribute__((ext_vector_type(4)));
typedef float f32x4 __attribute__((ext_vector_type(4)));
typedef __bf16 bf16x8 __attribute__((ext_vector_type(8)));

#define C2F 2.8853900817779268f

__device__ inline unsigned short f2bf(float f) {
    unsigned u = __float_as_uint(f);
    unsigned r = (u + 0x7fffu + ((u >> 16) & 1u)) >> 16;
    return (unsigned short)r;
}
__device__ inline float bf2f(unsigned short h) {
    return __uint_as_float(((unsigned)h) << 16);
}

__device__ inline void split_store(const f4 a0, const f4 a1,
                                   unsigned short* hip, unsigned short* lop) {
    float f[8];
    unsigned short h[8], l[8];
#pragma unroll
    for (int t = 0; t < 4; ++t) { f[t] = a0[t]; f[t + 4] = a1[t]; }
#pragma unroll
    for (int t = 0; t < 8; ++t) {
        h[t] = f2bf(f[t]);
        l[t] = f2bf(f[t] - bf2f(h[t]));
    }
    uint4 hv, lv;
    hv.x = (unsigned)h[0] | ((unsigned)h[1] << 16);
    hv.y = (unsigned)h[2] | ((unsigned)h[3] << 16);
    hv.z = (unsigned)h[4] | ((unsigned)h[5] << 16);
    hv.w = (unsigned)h[6] | ((unsigned)h[7] << 16);
    lv.x = (unsigned)l[0] | ((unsigned)l[1] << 16);
    lv.y = (unsigned)l[2] | ((unsigned)l[3] << 16);
    lv.z = (unsigned)l[4] | ((unsigned)l[5] << 16);
    lv.w = (unsigned)l[6] | ((unsigned)l[7] << 16);
    *(uint4*)hip = hv;
    *(uint4*)lop = lv;
}

// ---------------------------------------------------------------------------
// gemm_split: C[m,n] = act( sum_k A[m,k] * Wsel[n,k] + bias[n] )
// Wsel row n: n<256 -> Wa[n], else Wb[n-256].  ACT: 0=none, 1=tanh, 2=exp2(C2*x)
// ---------------------------------------------------------------------------
template <int ACT>
__global__ __launch_bounds__(256) void gemm_split(
    const float* __restrict__ A, const float* __restrict__ Wa,
    const float* __restrict__ Wb, const float* __restrict__ ba,
    const float* __restrict__ bb2, float* __restrict__ C, int Nn) {
    __shared__ unsigned short sAhi[64][40];
    __shared__ unsigned short sAlo[64][40];
    __shared__ unsigned short sBhi[64][40];
    __shared__ unsigned short sBlo[64][40];

    const int tid = threadIdx.x;
    const int m0 = blockIdx.x << 6;
    const int n0 = blockIdx.y << 6;
    const int lane = tid & 63;
    const int wv = tid >> 6;
    const int wm = wv >> 1, wn = wv & 1;
    const int fr = lane & 15;
    const int fks = (lane >> 4) << 3;

    f32x4 acc[2][2];
#pragma unroll
    for (int i = 0; i < 2; ++i)
#pragma unroll
        for (int j = 0; j < 2; ++j) acc[i][j] = (f32x4){0.f, 0.f, 0.f, 0.f};

    const int srow = tid >> 2;
    const int scol8 = (tid & 3) << 3;

    const float* Arow = &A[(size_t)(m0 + srow) * 256 + scol8];
    const int wrow = n0 + srow;
    const float* Wrow = (wrow < 256) ? &Wa[(size_t)wrow * 256 + scol8]
                                     : &Wb[(size_t)(wrow - 256) * 256 + scol8];

    for (int kt = 0; kt < 256; kt += 32) {
        f4 a0 = *(const f4*)(Arow + kt);
        f4 a1 = *(const f4*)(Arow + kt + 4);
        f4 w0 = *(const f4*)(Wrow + kt);
        f4 w1 = *(const f4*)(Wrow + kt + 4);
        split_store(a0, a1, &sAhi[srow][scol8], &sAlo[srow][scol8]);
        split_store(w0, w1, &sBhi[srow][scol8], &sBlo[srow][scol8]);
        __syncthreads();

        bf16x8 ah[2], al[2], bh[2], bl[2];
#pragma unroll
        for (int s = 0; s < 2; ++s) {
            ah[s] = *(const bf16x8*)&sAhi[(wm << 5) + (s << 4) + fr][fks];
            al[s] = *(const bf16x8*)&sAlo[(wm << 5) + (s << 4) + fr][fks];
            bh[s] = *(const bf16x8*)&sBhi[(wn << 5) + (s << 4) + fr][fks];
            bl[s] = *(const bf16x8*)&sBlo[(wn << 5) + (s << 4) + fr][fks];
        }
#pragma unroll
        for (int i = 0; i < 2; ++i)
#pragma unroll
            for (int j = 0; j < 2; ++j) {
                acc[i][j] = __builtin_amdgcn_mfma_f32_16x16x32_bf16(ah[i], bh[j], acc[i][j], 0, 0, 0);
                acc[i][j] = __builtin_amdgcn_mfma_f32_16x16x32_bf16(ah[i], bl[j], acc[i][j], 0, 0, 0);
                acc[i][j] = __builtin_amdgcn_mfma_f32_16x16x32_bf16(al[i], bh[j], acc[i][j], 0, 0, 0);
            }
        __syncthreads();
    }

    const int rbase = (lane >> 4) << 2;
#pragma unroll
    for (int i = 0; i < 2; ++i) {
#pragma unroll
        for (int j = 0; j < 2; ++j) {
            const int gcol = n0 + (wn << 5) + (j << 4) + fr;
            const float bias = (ACT == 2 && gcol >= 256) ? bb2[gcol - 256] : ba[gcol];
#pragma unroll
            for (int q = 0; q < 4; ++q) {
                const int grow = m0 + (wm << 5) + (i << 4) + rbase + q;
                float x = acc[i][j][q] + bias;
                if (ACT == 1)
                    x = 1.0f - 2.0f * __builtin_amdgcn_rcpf(
                                          1.0f + __builtin_amdgcn_exp2f(C2F * x));
                if (ACT == 2) x = __builtin_amdgcn_exp2f(C2F * x);
                C[(size_t)grow * Nn + gcol] = x;
            }
        }
    }
}

// ---------------------------------------------------------------------------
// gemm_nt: Wc[m,n] = sum_k Asel[m,k] * W2[k,n]   (B NOT transposed)
// Asel row m: m<256 -> Wq[m], else Wk[m-256].  M=512, N=256, K=256.
// Blocks with blockIdx.y==0 also compute bc[m] = sum_e Asel[m,e]*b2[e] + (bq|bk)[m]
// ---------------------------------------------------------------------------
__global__ __launch_bounds__(256) void gemm_nt(
    const float* __restrict__ Wq, const float* __restrict__ Wk,
    const float* __restrict__ W2, const float* __restrict__ b2,
    const float* __restrict__ bq, const float* __restrict__ bk,
    float* __restrict__ Wc, float* __restrict__ bc) {
    __shared__ unsigned short sAhi[64][40];
    __shared__ unsigned short sAlo[64][40];
    __shared__ unsigned short sBhi[64][40];
    __shared__ unsigned short sBlo[64][40];
    __shared__ float sred[64][4];

    const int tid = threadIdx.x;
    const int m0 = blockIdx.x << 6;
    const int n0 = blockIdx.y << 6;
    const int lane = tid & 63;
    const int wv = tid >> 6;
    const int wm = wv >> 1, wn = wv & 1;
    const int fr = lane & 15;
    const int fks = (lane >> 4) << 3;

    f32x4 acc[2][2];
#pragma unroll
    for (int i = 0; i < 2; ++i)
#pragma unroll
        for (int j = 0; j < 2; ++j) acc[i][j] = (f32x4){0.f, 0.f, 0.f, 0.f};

    const int srow = tid >> 2;
    const int scol8 = (tid & 3) << 3;
    const int arow = m0 + srow;
    const float* Arow = (arow < 256) ? &Wq[(size_t)arow * 256 + scol8]
                                     : &Wk[(size_t)(arow - 256) * 256 + scol8];
    // B staging: thread loads W2[kt+krow][n0+c8 .. +7]
    const int krow = tid >> 3;            // 0..31
    const int c8 = (tid & 7) << 3;        // 0..56

    for (int kt = 0; kt < 256; kt += 32) {
        f4 a0 = *(const f4*)(Arow + kt);
        f4 a1 = *(const f4*)(Arow + kt + 4);
        f4 w0 = *(const f4*)&W2[(size_t)(kt + krow) * 256 + n0 + c8];
        f4 w1 = *(const f4*)&W2[(size_t)(kt + krow) * 256 + n0 + c8 + 4];
        split_store(a0, a1, &sAhi[srow][scol8], &sAlo[srow][scol8]);
#pragma unroll
        for (int t = 0; t < 8; ++t) {
            float x = (t < 4) ? w0[t] : w1[t - 4];
            unsigned short hi = f2bf(x);
            sBhi[c8 + t][krow] = hi;
            sBlo[c8 + t][krow] = f2bf(x - bf2f(hi));
        }
        __syncthreads();

        bf16x8 ah[2], al[2], bh[2], bl[2];
#pragma unroll
        for (int s = 0; s < 2; ++s) {
            ah[s] = *(const bf16x8*)&sAhi[(wm << 5) + (s << 4) + fr][fks];
            al[s] = *(const bf16x8*)&sAlo[(wm << 5) + (s << 4) + fr][fks];
            bh[s] = *(const bf16x8*)&sBhi[(wn << 5) + (s << 4) + fr][fks];
            bl[s] = *(const bf16x8*)&sBlo[(wn << 5) + (s << 4) + fr][fks];
        }
#pragma unroll
        for (int i = 0; i < 2; ++i)
#pragma unroll
            for (int j = 0; j < 2; ++j) {
                acc[i][j] = __builtin_amdgcn_mfma_f32_16x16x32_bf16(ah[i], bh[j], acc[i][j], 0, 0, 0);
                acc[i][j] = __builtin_amdgcn_mfma_f32_16x16x32_bf16(ah[i], bl[j], acc[i][j], 0, 0, 0);
                acc[i][j] = __builtin_amdgcn_mfma_f32_16x16x32_bf16(al[i], bh[j], acc[i][j], 0, 0, 0);
            }
        __syncthreads();
    }

    const int rbase = (lane >> 4) << 2;
#pragma unroll
    for (int i = 0; i < 2; ++i)
#pragma unroll
        for (int j = 0; j < 2; ++j) {
            const int gcol = n0 + (wn << 5) + (j << 4) + fr;
#pragma unroll
            for (int q = 0; q < 4; ++q) {
                const int grow = m0 + (wm << 5) + (i << 4) + rbase + q;
                Wc[(size_t)grow * 256 + gcol] = acc[i][j][q];
            }
        }

    // bias combine on n-tile-0 blocks
    if (blockIdx.y == 0) {
        const int rr = tid >> 2;
        const int part = (tid & 3) << 6;
        const int grow = m0 + rr;
        const float* Ar = (grow < 256) ? &Wq[(size_t)grow * 256]
                                       : &Wk[(size_t)(grow - 256) * 256];
        float s = 0.f;
#pragma unroll
        for (int e = 0; e < 64; e += 4) {
            f4 a = *(const f4*)&Ar[part + e];
            f4 bbv = *(const f4*)&b2[part + e];
            s += a[0] * bbv[0] + a[1] * bbv[1] + a[2] * bbv[2] + a[3] * bbv[3];
        }
        sred[rr][tid & 3] = s;
        __syncthreads();
        if (tid < 64) {
            float bias = sred[tid][0] + sred[tid][1] + sred[tid][2] + sred[tid][3];
            const int g2 = m0 + tid;
            bias += (g2 < 256) ? bq[g2] : bk[g2 - 256];
            bc[g2] = bias;
        }
    }
}

// ---------------------------------------------------------------------------
// Pairwise: Ep[b,i,j] = sum_h v_h * rcp(1 + u[b,i,h]*w[b,j,h])
// uwb: [2048 x 512]; u = cols [0,256), w = cols [256,512)
// 512 threads, 64x64 tile, h chunked by 64 with double-buffered LDS.
// ---------------------------------------------------------------------------
__global__ __launch_bounds__(512, 2) void pairwise_kernel(
    const float* __restrict__ uwb, const float* __restrict__ v,
    float* __restrict__ Ep) {
    __shared__ float sU[2][64][68];
    __shared__ float sW[2][64][68];
    __shared__ float sV[256];

    const int tid = threadIdx.x;
    const int bb = blockIdx.x;
    const int b = bb >> 6;
    const int i0 = ((bb >> 3) & 7) << 6;
    const int j0 = (bb & 7) << 6;

    const float* ubase = uwb + (size_t)((b << 9) + i0) * 512;
    const float* wbase = uwb + (size_t)((b << 9) + j0) * 512 + 256;

    const int sr = tid >> 4;            // 0..31
    const int sc = (tid & 15) << 2;     // 0..60

    // prologue: stage chunk 0 directly
    *(f4*)&sU[0][sr][sc]      = *(const f4*)&ubase[(size_t)sr * 512 + sc];
    *(f4*)&sU[0][sr + 32][sc] = *(const f4*)&ubase[(size_t)(sr + 32) * 512 + sc];
    *(f4*)&sW[0][sr][sc]      = *(const f4*)&wbase[(size_t)sr * 512 + sc];
    *(f4*)&sW[0][sr + 32][sc] = *(const f4*)&wbase[(size_t)(sr + 32) * 512 + sc];
    if (tid < 64) *(f4*)&sV[tid << 2] = *(const f4*)&v[tid << 2];
    __syncthreads();

    const int ty = tid >> 5;   // 0..15 -> rows ty + 16d
    const int tx = tid & 31;   // 0..31 -> cols tx + 32e

    f2 acc[4][2];
#pragma unroll
    for (int d = 0; d < 4; ++d)
#pragma unroll
        for (int e = 0; e < 2; ++e) acc[d][e] = (f2){0.f, 0.f};

    const f2 kOne2 = (f2){1.f, 1.f};

#define COMPUTE_HALF(buf, vb, h0)                                              \
    {                                                                          \
        _Pragma("unroll 4") for (int hh = (h0); hh < (h0) + 32; hh += 4) {     \
            f4 vv = *(const f4*)&sV[(vb) + hh];                                \
            f4 uu[4], ww[2];                                                   \
            _Pragma("unroll") for (int d = 0; d < 4; ++d)                      \
                uu[d] = *(const f4*)&sU[buf][ty + (d << 4)][hh];               \
            _Pragma("unroll") for (int e = 0; e < 2; ++e)                      \
                ww[e] = *(const f4*)&sW[buf][tx + (e << 5)][hh];               \
            f2 v01 = (f2){vv[0], vv[1]}, v23 = (f2){vv[2], vv[3]};             \
            _Pragma("unroll") for (int d = 0; d < 4; ++d)                      \
            _Pragma("unroll") for (int e = 0; e < 2; ++e) {                    \
                f2 ua = (f2){uu[d][0], uu[d][1]}, ub = (f2){uu[d][2], uu[d][3]}; \
                f2 wa = (f2){ww[e][0], ww[e][1]}, wb = (f2){ww[e][2], ww[e][3]}; \
                f2 d0 = __builtin_elementwise_fma(ua, wa, kOne2);              \
                f2 d1 = __builtin_elementwise_fma(ub, wb, kOne2);              \
                f2 r0 = (f2){__builtin_amdgcn_rcpf(d0.x),                      \
                             __builtin_amdgcn_rcpf(d0.y)};                     \
                f2 r1 = (f2){__builtin_amdgcn_rcpf(d1.x),                      \
                             __builtin_amdgcn_rcpf(d1.y)};                     \
                acc[d][e] = __builtin_elementwise_fma(v01, r0, acc[d][e]);     \
                acc[d][e] = __builtin_elementwise_fma(v23, r1, acc[d][e]);     \
            }                                                                  \
        }                                                                      \
    }

    for (int ch = 0; ch < 4; ++ch) {
        const int cur = ch & 1;
        const int vb = ch << 6;
        f4 pu0, pu1, pw0, pw1;
        if (ch < 3) {
            const int hc = (ch + 1) << 6;
            pu0 = *(const f4*)&ubase[(size_t)sr * 512 + hc + sc];
            pu1 = *(const f4*)&ubase[(size_t)(sr + 32) * 512 + hc + sc];
            pw0 = *(const f4*)&wbase[(size_t)sr * 512 + hc + sc];
            pw1 = *(const f4*)&wbase[(size_t)(sr + 32) * 512 + hc + sc];
        }
        COMPUTE_HALF(cur, vb, 0)
        if (ch < 3) {
            const int nb = cur ^ 1;
            *(f4*)&sU[nb][sr][sc] = pu0;
            *(f4*)&sU[nb][sr + 32][sc] = pu1;
            *(f4*)&sW[nb][sr][sc] = pw0;
            *(f4*)&sW[nb][sr + 32][sc] = pw1;
        }
        COMPUTE_HALF(cur, vb, 32)
        __syncthreads();
    }
#undef COMPUTE_HALF

#pragma unroll
    for (int d = 0; d < 4; ++d)
#pragma unroll
        for (int e = 0; e < 2; ++e) {
            const float r = acc[d][e].x + acc[d][e].y;
            Ep[(size_t)((b << 9) + i0 + ty + (d << 4)) * 512 + j0 + tx + (e << 5)] = r;
        }
}

// out[b,i,j] = S_v - (Ep[b,i,j] + Ep[b,j,i])
__global__ __launch_bounds__(256) void sym_kernel(const float* __restrict__ Ep,
                                                  const float* __restrict__ v,
                                                  float* __restrict__ out) {
    __shared__ float t1[64][65];
    __shared__ float t2[64][65];
    __shared__ float red[4];

    const int tid = threadIdx.x;
    const int lane = tid & 63, wv = tid >> 6;

    float x = v[tid];
#pragma unroll
    for (int o = 32; o > 0; o >>= 1) x += __shfl_xor(x, o, 64);
    if (lane == 0) red[wv] = x;

    const int bb = blockIdx.x;
    const int b = bb >> 6;
    const int i0 = ((bb >> 3) & 7) << 6;
    const int j0 = (bb & 7) << 6;

    for (int idx = tid; idx < 4096; idx += 256) {
        const int r = idx >> 6, c = idx & 63;
        t1[r][c] = Ep[(size_t)((b << 9) + i0 + r) * 512 + j0 + c];
        t2[r][c] = Ep[(size_t)((b << 9) + j0 + r) * 512 + i0 + c];
    }
    __syncthreads();
    const float Sv = red[0] + red[1] + red[2] + red[3];
    for (int idx = tid; idx < 4096; idx += 256) {
        const int r = idx >> 6, c = idx & 63;
        out[(size_t)((b << 9) + i0 + r) * 512 + j0 + c] = Sv - (t1[r][c] + t2[c][r]);
    }
}

extern "C" void kernel_launch(void* const* d_in, const int* in_sizes, int n_in,
                              void* d_out, int out_size, void* d_ws, size_t ws_size,
                              hipStream_t stream) {
    const float* X  = (const float*)d_in[0];
    // d_in[1] = Y (unused)
    const float* W1 = (const float*)d_in[2];
    const float* b1 = (const float*)d_in[3];
    const float* W2 = (const float*)d_in[4];
    const float* b2 = (const float*)d_in[5];
    const float* Wq = (const float*)d_in[6];
    const float* bq = (const float*)d_in[7];
    const float* Wk = (const float*)d_in[8];
    const float* bk = (const float*)d_in[9];
    const float* v  = (const float*)d_in[10];
    // d_in[11] = k (unused)

    float* ws  = (float*)d_ws;
    float* h1  = ws;                   // 2048*256 = 524288 f
    float* uwb = ws + 524288;          // 2048*512 = 1048576 f
    float* Ep  = ws + 1572864;         // 4*512*512 = 1048576 f
    float* Wc  = ws + 2621440;         // 512*256 = 131072 f
    float* bc  = ws + 2752512;         // 512 f
    float* out = (float*)d_out;

    // Wc = [Wq;Wk] @ W2, bc = [Wq@b2+bq; Wk@b2+bk]
    gemm_nt<<<dim3(8, 4), 256, 0, stream>>>(Wq, Wk, W2, b2, bq, bk, Wc, bc);
    // h1 = tanh(X @ W1^T + b1)
    gemm_split<1><<<dim3(32, 4), 256, 0, stream>>>(X, W1, W1, b1, b1, h1, 256);
    // uwb[:, :256] = exp2(C2*(h1@Wq'^T+bq')), uwb[:, 256:] = exp2(C2*(h1@Wk'^T+bk'))
    gemm_split<2><<<dim3(32, 8), 256, 0, stream>>>(h1, Wc, Wc + 65536, bc, bc + 256, uwb, 512);
    // Ep[b,i,j] = sum_h v_h * rcp(1 + u*w)
    pairwise_kernel<<<256, 512, 0, stream>>>(uwb, v, Ep);
    // out = S_v - (Ep + Ep^T)
    sym_kernel<<<256, 256, 0, stream>>>(Ep, v, out);
}

// Round 3
// 69.893 us; speedup vs baseline: 1.2167x; 1.0922x over previous
//
#include <hip/hip_runtime.h>

// Problem: B=4, N=512, D=256, H=256, M = B*N = 2048
// out[b,i,j] = 0.5*(E + E^T),  E[b,i,j] = sum_h v[h]*tanh(Q[b,i,h]+K[b,j,h])
// tanh(q+k) = 1 - 2/(1+e^{2q}e^{2k}); u=exp2(C2*q), w=exp2(C2*k), C2=2*log2(e)
// c_ij = Sv/2 - sum_h v_h/(1+u_ih w_jh);  out_ij = c_ij + c_ji
// Pairing (1 rcp per 2 h): v0/(1+a)+v1/(1+b) = (v0*b'+v1*a')/(a'*b'), a'=1+a,b'=1+b
// GEMM fold: Q = h1 @ (Wq@W2)^T + (Wq@b2+bq)  (no activation between fc2 and Q/K)

typedef float f2 __attribute__((ext_vector_type(2)));
typedef float f4 __attribute__((ext_vector_type(4)));
typedef float f32x4 __attribute__((ext_vector_type(4)));
typedef __bf16 bf16x8 __attribute__((ext_vector_type(8)));

#define C2F 2.8853900817779268f

__device__ inline unsigned short f2bf(float f) {
    unsigned u = __float_as_uint(f);
    unsigned r = (u + 0x7fffu + ((u >> 16) & 1u)) >> 16;
    return (unsigned short)r;
}
__device__ inline float bf2f(unsigned short h) {
    return __uint_as_float(((unsigned)h) << 16);
}

__device__ inline void split4(const f4 a, unsigned short* hp, unsigned short* lp) {
    unsigned short h[4], l[4];
#pragma unroll
    for (int t = 0; t < 4; ++t) {
        h[t] = f2bf(a[t]);
        l[t] = f2bf(a[t] - bf2f(h[t]));
    }
    uint2 hv, lv;
    hv.x = (unsigned)h[0] | ((unsigned)h[1] << 16);
    hv.y = (unsigned)h[2] | ((unsigned)h[3] << 16);
    lv.x = (unsigned)l[0] | ((unsigned)l[1] << 16);
    lv.y = (unsigned)l[2] | ((unsigned)l[3] << 16);
    *(uint2*)hp = hv;
    *(uint2*)lp = lv;
}

// ---------------------------------------------------------------------------
// gemm_fullk: C[m,n] = act( sum_k A[m,k]*Wsel[n,k] + bias[n] ), K=256 resident.
// Wsel row n: n<256 -> Wa[n], else Wb[n-256].  ACT: 0=none, 1=tanh, 2=exp2(C2*x)
// One barrier: stage full K -> 96 straight-line MFMAs.
// ---------------------------------------------------------------------------
template <int ACT>
__global__ __launch_bounds__(256) void gemm_fullk(
    const float* __restrict__ A, const float* __restrict__ Wa,
    const float* __restrict__ Wb, const float* __restrict__ ba,
    const float* __restrict__ bb2, float* __restrict__ C, int Nn) {
    __shared__ unsigned short sAhi[64][264];
    __shared__ unsigned short sAlo[64][264];
    __shared__ unsigned short sBhi[64][264];
    __shared__ unsigned short sBlo[64][264];

    const int tid = threadIdx.x;
    const int m0 = blockIdx.x << 6;
    const int n0 = blockIdx.y << 6;

    // coalesced staging: both tiles are contiguous 64KB blocks
    const float* Atile = A + (size_t)m0 * 256;
    const float* Wtile = (n0 < 256) ? (Wa + (size_t)n0 * 256)
                                    : (Wb + (size_t)(n0 - 256) * 256);
    const int col4 = (tid & 63) << 2;  // 0..252
    const int rgrp = tid >> 6;         // 0..3
#pragma unroll
    for (int t = 0; t < 16; ++t) {
        const int row = (t << 2) + rgrp;
        f4 av = *(const f4*)&Atile[(size_t)row * 256 + col4];
        f4 wv = *(const f4*)&Wtile[(size_t)row * 256 + col4];
        split4(av, &sAhi[row][col4], &sAlo[row][col4]);
        split4(wv, &sBhi[row][col4], &sBlo[row][col4]);
    }
    __syncthreads();

    const int lane = tid & 63;
    const int wav = tid >> 6;
    const int wm = wav >> 1, wn = wav & 1;
    const int fr = lane & 15;
    const int fks = (lane >> 4) << 3;

    f32x4 acc[2][2];
#pragma unroll
    for (int i = 0; i < 2; ++i)
#pragma unroll
        for (int j = 0; j < 2; ++j) acc[i][j] = (f32x4){0.f, 0.f, 0.f, 0.f};

#pragma unroll
    for (int kt = 0; kt < 256; kt += 32) {
        bf16x8 ah[2], al[2], bh[2], bl[2];
#pragma unroll
        for (int s = 0; s < 2; ++s) {
            ah[s] = *(const bf16x8*)&sAhi[(wm << 5) + (s << 4) + fr][kt + fks];
            al[s] = *(const bf16x8*)&sAlo[(wm << 5) + (s << 4) + fr][kt + fks];
            bh[s] = *(const bf16x8*)&sBhi[(wn << 5) + (s << 4) + fr][kt + fks];
            bl[s] = *(const bf16x8*)&sBlo[(wn << 5) + (s << 4) + fr][kt + fks];
        }
#pragma unroll
        for (int i = 0; i < 2; ++i)
#pragma unroll
            for (int j = 0; j < 2; ++j) {
                acc[i][j] = __builtin_amdgcn_mfma_f32_16x16x32_bf16(ah[i], bh[j], acc[i][j], 0, 0, 0);
                acc[i][j] = __builtin_amdgcn_mfma_f32_16x16x32_bf16(ah[i], bl[j], acc[i][j], 0, 0, 0);
                acc[i][j] = __builtin_amdgcn_mfma_f32_16x16x32_bf16(al[i], bh[j], acc[i][j], 0, 0, 0);
            }
    }

    const int rbase = (lane >> 4) << 2;
#pragma unroll
    for (int i = 0; i < 2; ++i) {
#pragma unroll
        for (int j = 0; j < 2; ++j) {
            const int gcol = n0 + (wn << 5) + (j << 4) + fr;
            const float bias = (ACT == 2 && gcol >= 256) ? bb2[gcol - 256] : ba[gcol];
#pragma unroll
            for (int q = 0; q < 4; ++q) {
                const int grow = m0 + (wm << 5) + (i << 4) + rbase + q;
                float x = acc[i][j][q] + bias;
                if (ACT == 1)
                    x = 1.0f - 2.0f * __builtin_amdgcn_rcpf(
                                          1.0f + __builtin_amdgcn_exp2f(C2F * x));
                if (ACT == 2) x = __builtin_amdgcn_exp2f(C2F * x);
                C[(size_t)grow * Nn + gcol] = x;
            }
        }
    }
}

// ---------------------------------------------------------------------------
// gemm_nt_fullk: Wc[m,n] = sum_k Asel[m,k]*W2[k,n]  (B not transposed), K res.
// Asel row m: m<256 -> Wq[m], else Wk[m-256].  Also bc[m] = Asel[m]·b2 + bias.
// ---------------------------------------------------------------------------
__global__ __launch_bounds__(256) void gemm_nt_fullk(
    const float* __restrict__ Wq, const float* __restrict__ Wk,
    const float* __restrict__ W2, const float* __restrict__ b2,
    const float* __restrict__ bq, const float* __restrict__ bk,
    float* __restrict__ Wc, float* __restrict__ bc) {
    __shared__ unsigned short sAhi[64][264];
    __shared__ unsigned short sAlo[64][264];
    __shared__ unsigned short sBhi[64][264];
    __shared__ unsigned short sBlo[64][264];
    __shared__ float sred[64][4];

    const int tid = threadIdx.x;
    const int m0 = blockIdx.x << 6;
    const int n0 = blockIdx.y << 6;

    const float* Atile = (m0 < 256) ? (Wq + (size_t)m0 * 256)
                                    : (Wk + (size_t)(m0 - 256) * 256);
    const int col4 = (tid & 63) << 2;
    const int rgrp = tid >> 6;
#pragma unroll
    for (int t = 0; t < 16; ++t) {
        const int row = (t << 2) + rgrp;
        f4 av = *(const f4*)&Atile[(size_t)row * 256 + col4];
        split4(av, &sAhi[row][col4], &sAlo[row][col4]);
    }
    // B transposed staging: sB[n][k] = W2[k][n0+n]
    const int c4 = (tid & 15) << 2;   // 0..60
    const int kg = tid >> 4;          // 0..15
#pragma unroll
    for (int t = 0; t < 16; ++t) {
        const int k = (t << 4) + kg;
        f4 wv = *(const f4*)&W2[(size_t)k * 256 + n0 + c4];
#pragma unroll
        for (int q = 0; q < 4; ++q) {
            unsigned short hi = f2bf(wv[q]);
            sBhi[c4 + q][k] = hi;
            sBlo[c4 + q][k] = f2bf(wv[q] - bf2f(hi));
        }
    }
    __syncthreads();

    const int lane = tid & 63;
    const int wav = tid >> 6;
    const int wm = wav >> 1, wn = wav & 1;
    const int fr = lane & 15;
    const int fks = (lane >> 4) << 3;

    f32x4 acc[2][2];
#pragma unroll
    for (int i = 0; i < 2; ++i)
#pragma unroll
        for (int j = 0; j < 2; ++j) acc[i][j] = (f32x4){0.f, 0.f, 0.f, 0.f};

#pragma unroll
    for (int kt = 0; kt < 256; kt += 32) {
        bf16x8 ah[2], al[2], bh[2], bl[2];
#pragma unroll
        for (int s = 0; s < 2; ++s) {
            ah[s] = *(const bf16x8*)&sAhi[(wm << 5) + (s << 4) + fr][kt + fks];
            al[s] = *(const bf16x8*)&sAlo[(wm << 5) + (s << 4) + fr][kt + fks];
            bh[s] = *(const bf16x8*)&sBhi[(wn << 5) + (s << 4) + fr][kt + fks];
            bl[s] = *(const bf16x8*)&sBlo[(wn << 5) + (s << 4) + fr][kt + fks];
        }
#pragma unroll
        for (int i = 0; i < 2; ++i)
#pragma unroll
            for (int j = 0; j < 2; ++j) {
                acc[i][j] = __builtin_amdgcn_mfma_f32_16x16x32_bf16(ah[i], bh[j], acc[i][j], 0, 0, 0);
                acc[i][j] = __builtin_amdgcn_mfma_f32_16x16x32_bf16(ah[i], bl[j], acc[i][j], 0, 0, 0);
                acc[i][j] = __builtin_amdgcn_mfma_f32_16x16x32_bf16(al[i], bh[j], acc[i][j], 0, 0, 0);
            }
    }

    const int rbase = (lane >> 4) << 2;
#pragma unroll
    for (int i = 0; i < 2; ++i)
#pragma unroll
        for (int j = 0; j < 2; ++j) {
            const int gcol = n0 + (wn << 5) + (j << 4) + fr;
#pragma unroll
            for (int q = 0; q < 4; ++q) {
                const int grow = m0 + (wm << 5) + (i << 4) + rbase + q;
                Wc[(size_t)grow * 256 + gcol] = acc[i][j][q];
            }
        }

    if (blockIdx.y == 0) {
        const int rr = tid >> 2;
        const int part = (tid & 3) << 6;
        const int grow = m0 + rr;
        const float* Ar = (grow < 256) ? &Wq[(size_t)grow * 256]
                                       : &Wk[(size_t)(grow - 256) * 256];
        float s = 0.f;
#pragma unroll
        for (int e = 0; e < 64; e += 4) {
            f4 a = *(const f4*)&Ar[part + e];
            f4 bv = *(const f4*)&b2[part + e];
            s += a[0] * bv[0] + a[1] * bv[1] + a[2] * bv[2] + a[3] * bv[3];
        }
        sred[rr][tid & 3] = s;
        __syncthreads();
        if (tid < 64) {
            float bias = sred[tid][0] + sred[tid][1] + sred[tid][2] + sred[tid][3];
            const int g2 = m0 + tid;
            bias += (g2 < 256) ? bq[g2] : bk[g2 - 256];
            bc[g2] = bias;
        }
    }
}

// ---------------------------------------------------------------------------
// pairwise: per (b, i-tile, j-tile, h-half) block computes
//   c[i,j] = 0.5*svH - sum_{h in half} v_h/(1+u_ih w_jh)
// and atomicAdds c into out[i,j] and out[j,i].  512 thr, 64x64 tile, h=128.
// ---------------------------------------------------------------------------
__global__ __launch_bounds__(512, 4) void pairwise_kernel(
    const float* __restrict__ uwb, const float* __restrict__ v,
    float* __restrict__ out) {
    __shared__ float sU[2][64][68];
    __shared__ float sW[2][64][68];
    __shared__ float sV[128];

    const int tid = threadIdx.x;
    const int bb = blockIdx.x;       // 512 = 4b * 64 tiles * 2 halves
    const int hh = (bb & 1) << 7;    // h-half offset
    const int tt = bb >> 1;
    const int b = tt >> 6;
    const int i0 = ((tt >> 3) & 7) << 6;
    const int j0 = (tt & 7) << 6;

    const float* ubase = uwb + (size_t)((b << 9) + i0) * 512 + hh;
    const float* wbase = uwb + (size_t)((b << 9) + j0) * 512 + 256 + hh;

    const int sr = tid >> 3;         // 0..63
    const int sc = (tid & 7) << 3;   // 0,8,..,56

    // stage chunk 0 (h 0..63 of the half) + sV
    {
        f4 a0 = *(const f4*)&ubase[(size_t)sr * 512 + sc];
        f4 a1 = *(const f4*)&ubase[(size_t)sr * 512 + sc + 4];
        f4 b0 = *(const f4*)&wbase[(size_t)sr * 512 + sc];
        f4 b1 = *(const f4*)&wbase[(size_t)sr * 512 + sc + 4];
        *(f4*)&sU[0][sr][sc] = a0;
        *(f4*)&sU[0][sr][sc + 4] = a1;
        *(f4*)&sW[0][sr][sc] = b0;
        *(f4*)&sW[0][sr][sc + 4] = b1;
    }
    if (tid < 32) *(f4*)&sV[tid << 2] = *(const f4*)&v[hh + (tid << 2)];
    __syncthreads();

    const int ty = tid >> 5;   // 0..15: rows ty+16d
    const int tx = tid & 31;   // 0..31: cols tx+32e

    float acc[4][2];
#pragma unroll
    for (int d = 0; d < 4; ++d)
#pragma unroll
        for (int e = 0; e < 2; ++e) acc[d][e] = 0.f;

    const f2 one2 = (f2){1.f, 1.f};

#define COMPUTE_CHUNK(buf, vb)                                                  \
    {                                                                           \
        _Pragma("unroll 2") for (int h4 = 0; h4 < 64; h4 += 4) {                \
            f4 vv = *(const f4*)&sV[(vb) + h4];                                 \
            f4 uu[4], ww[2];                                                    \
            _Pragma("unroll") for (int d = 0; d < 4; ++d)                       \
                uu[d] = *(const f4*)&sU[buf][ty + (d << 4)][h4];                \
            _Pragma("unroll") for (int e = 0; e < 2; ++e)                       \
                ww[e] = *(const f4*)&sW[buf][tx + (e << 5)][h4];                \
            _Pragma("unroll") for (int d = 0; d < 4; ++d)                       \
            _Pragma("unroll") for (int e = 0; e < 2; ++e) {                     \
                f2 u01 = (f2){uu[d][0], uu[d][1]};                              \
                f2 u23 = (f2){uu[d][2], uu[d][3]};                              \
                f2 w01 = (f2){ww[e][0], ww[e][1]};                              \
                f2 w23 = (f2){ww[e][2], ww[e][3]};                              \
                f2 p1 = __builtin_elementwise_fma(u01, w01, one2);              \
                f2 p2 = __builtin_elementwise_fma(u23, w23, one2);              \
                float den1 = p1[0] * p1[1];                                     \
                float den2 = p2[0] * p2[1];                                     \
                float num1 = fmaf(vv[1], p1[0], vv[0] * p1[1]);                 \
                float num2 = fmaf(vv[3], p2[0], vv[2] * p2[1]);                 \
                acc[d][e] = fmaf(num1, __builtin_amdgcn_rcpf(den1), acc[d][e]); \
                acc[d][e] = fmaf(num2, __builtin_amdgcn_rcpf(den2), acc[d][e]); \
            }                                                                   \
        }                                                                       \
    }

    // prefetch chunk 1 into registers
    f4 pa0 = *(const f4*)&ubase[(size_t)sr * 512 + 64 + sc];
    f4 pa1 = *(const f4*)&ubase[(size_t)sr * 512 + 64 + sc + 4];
    f4 pb0 = *(const f4*)&wbase[(size_t)sr * 512 + 64 + sc];
    f4 pb1 = *(const f4*)&wbase[(size_t)sr * 512 + 64 + sc + 4];

    COMPUTE_CHUNK(0, 0)

    *(f4*)&sU[1][sr][sc] = pa0;
    *(f4*)&sU[1][sr][sc + 4] = pa1;
    *(f4*)&sW[1][sr][sc] = pb0;
    *(f4*)&sW[1][sr][sc + 4] = pb1;
    __syncthreads();

    COMPUTE_CHUNK(1, 64)
#undef COMPUTE_CHUNK

    // svH = sum of v over this half
    float sv = 0.f;
#pragma unroll
    for (int k = 0; k < 128; k += 4) {
        f4 t = *(const f4*)&sV[k];
        sv += (t[0] + t[1]) + (t[2] + t[3]);
    }

    float c[4][2];
#pragma unroll
    for (int d = 0; d < 4; ++d)
#pragma unroll
        for (int e = 0; e < 2; ++e) c[d][e] = fmaf(0.5f, sv, -acc[d][e]);

    // direct scatter: out[i0+.., j0+..] += c  (coalesced)
    float* obase = out + (size_t)((b << 9) + i0) * 512 + j0;
#pragma unroll
    for (int d = 0; d < 4; ++d)
#pragma unroll
        for (int e = 0; e < 2; ++e)
            atomicAdd(&obase[(size_t)(ty + (d << 4)) * 512 + tx + (e << 5)], c[d][e]);

    // mirror scatter via LDS transpose: out[j0+r, i0+col] += c[col][r]
    float(*sT)[68] = sU[0];   // safe: nobody reads sU[0] anymore
#pragma unroll
    for (int d = 0; d < 4; ++d)
#pragma unroll
        for (int e = 0; e < 2; ++e)
            sT[ty + (d << 4)][tx + (e << 5)] = c[d][e];
    __syncthreads();

    const int wv_ = tid >> 6;       // 0..7
    const int lane = tid & 63;      // column of mirror tile
    float* mbase = out + (size_t)((b << 9) + j0) * 512 + i0;
#pragma unroll
    for (int it = 0; it < 8; ++it) {
        const int r = (it << 3) + wv_;
        atomicAdd(&mbase[(size_t)r * 512 + lane], sT[lane][r]);
    }
}

extern "C" void kernel_launch(void* const* d_in, const int* in_sizes, int n_in,
                              void* d_out, int out_size, void* d_ws, size_t ws_size,
                              hipStream_t stream) {
    const float* X  = (const float*)d_in[0];
    // d_in[1] = Y (unused)
    const float* W1 = (const float*)d_in[2];
    const float* b1 = (const float*)d_in[3];
    const float* W2 = (const float*)d_in[4];
    const float* b2 = (const float*)d_in[5];
    const float* Wq = (const float*)d_in[6];
    const float* bq = (const float*)d_in[7];
    const float* Wk = (const float*)d_in[8];
    const float* bk = (const float*)d_in[9];
    const float* v  = (const float*)d_in[10];
    // d_in[11] = k (unused)

    float* ws  = (float*)d_ws;
    float* h1  = ws;                 // 2048*256 = 524288 f
    float* uwb = ws + 524288;        // 2048*512 = 1048576 f
    float* Wc  = ws + 1572864;       // 512*256  = 131072 f
    float* bc  = ws + 1703936;       // 512 f
    float* out = (float*)d_out;

    // zero the output (pairwise accumulates atomically)
    hipMemsetAsync(out, 0, (size_t)out_size * sizeof(float), stream);

    // Wc = [Wq;Wk] @ W2, bc = [Wq@b2+bq; Wk@b2+bk]
    gemm_nt_fullk<<<dim3(8, 4), 256, 0, stream>>>(Wq, Wk, W2, b2, bq, bk, Wc, bc);
    // h1 = tanh(X @ W1^T + b1)
    gemm_fullk<1><<<dim3(32, 4), 256, 0, stream>>>(X, W1, W1, b1, b1, h1, 256);
    // uwb[:, :256] = exp2(C2*Q), uwb[:, 256:] = exp2(C2*K)
    gemm_fullk<2><<<dim3(32, 8), 256, 0, stream>>>(h1, Wc, Wc + 65536, bc, bc + 256, uwb, 512);
    // out[i,j] += c_ij and c_ji
    pairwise_kernel<<<512, 512, 0, stream>>>(uwb, v, out);
}

// Round 4
// 61.604 us; speedup vs baseline: 1.3804x; 1.1345x over previous
//
#include <hip/hip_runtime.h>

// Problem: B=4, N=512, D=256, H=256, M = B*N = 2048
// out[b,i,j] = 0.5*(E + E^T),  E[b,i,j] = sum_h v[h]*tanh(Q[b,i,h]+K[b,j,h])
// tanh(q+k) = 1 - 2/(1+e^{2q}e^{2k}); u=exp2(C2*q), w=exp2(C2*k), C2=2*log2(e)
// P_ij = sum_h v_h/(1+u_ih w_jh);  out_ij = Sv - (P_ij + P_ji)
// 4-way rcp batching: sum_t v_t/A_t = (t01*m23 + t23*m01)/(m01*m23),
//   A_t = 1+u_t w_t, m01=A0*A1, m23=A2*A3, t01=v0*A1+v1*A0, t23=v2*A3+v3*A2.
//   Safe: u,w clamped <= 1e4 in gemm3 epilogue -> P <= ~1e32 (no overflow);
//   clamp error <= 1e-8 per term (tanh saturated).
// GEMM fold: Q = h1 @ (Wq@W2)^T + (Wq@b2+bq)  (no activation between fc2, Q/K)

typedef float f2 __attribute__((ext_vector_type(2)));
typedef float f4 __attribute__((ext_vector_type(4)));
typedef float f32x4 __attribute__((ext_vector_type(4)));
typedef __bf16 bf16x8 __attribute__((ext_vector_type(8)));

#define C2F 2.8853900817779268f

__device__ inline unsigned short f2bf(float f) {
    unsigned u = __float_as_uint(f);
    unsigned r = (u + 0x7fffu + ((u >> 16) & 1u)) >> 16;
    return (unsigned short)r;
}
__device__ inline float bf2f(unsigned short h) {
    return __uint_as_float(((unsigned)h) << 16);
}

__device__ inline void split4(const f4 a, unsigned short* hp, unsigned short* lp) {
    unsigned short h[4], l[4];
#pragma unroll
    for (int t = 0; t < 4; ++t) {
        h[t] = f2bf(a[t]);
        l[t] = f2bf(a[t] - bf2f(h[t]));
    }
    uint2 hv, lv;
    hv.x = (unsigned)h[0] | ((unsigned)h[1] << 16);
    hv.y = (unsigned)h[2] | ((unsigned)h[3] << 16);
    lv.x = (unsigned)l[0] | ((unsigned)l[1] << 16);
    lv.y = (unsigned)l[2] | ((unsigned)l[3] << 16);
    *(uint2*)hp = hv;
    *(uint2*)lp = lv;
}

// ---------------------------------------------------------------------------
// gemm_fullk: C[m,n] = act( sum_k A[m,k]*Wsel[n,k] + bias[n] ), K=256 resident.
// ACT: 1=tanh, 2=exp2(C2*x) clamped to [0,1e4]
// ---------------------------------------------------------------------------
template <int ACT>
__global__ __launch_bounds__(256) void gemm_fullk(
    const float* __restrict__ A, const float* __restrict__ Wa,
    const float* __restrict__ Wb, const float* __restrict__ ba,
    const float* __restrict__ bb2, float* __restrict__ C, int Nn) {
    __shared__ unsigned short sAhi[64][264];
    __shared__ unsigned short sAlo[64][264];
    __shared__ unsigned short sBhi[64][264];
    __shared__ unsigned short sBlo[64][264];

    const int tid = threadIdx.x;
    const int m0 = blockIdx.x << 6;
    const int n0 = blockIdx.y << 6;

    const float* Atile = A + (size_t)m0 * 256;
    const float* Wtile = (n0 < 256) ? (Wa + (size_t)n0 * 256)
                                    : (Wb + (size_t)(n0 - 256) * 256);
    const int col4 = (tid & 63) << 2;
    const int rgrp = tid >> 6;
#pragma unroll
    for (int t = 0; t < 16; ++t) {
        const int row = (t << 2) + rgrp;
        f4 av = *(const f4*)&Atile[(size_t)row * 256 + col4];
        f4 wv = *(const f4*)&Wtile[(size_t)row * 256 + col4];
        split4(av, &sAhi[row][col4], &sAlo[row][col4]);
        split4(wv, &sBhi[row][col4], &sBlo[row][col4]);
    }
    __syncthreads();

    const int lane = tid & 63;
    const int wav = tid >> 6;
    const int wm = wav >> 1, wn = wav & 1;
    const int fr = lane & 15;
    const int fks = (lane >> 4) << 3;

    f32x4 acc[2][2];
#pragma unroll
    for (int i = 0; i < 2; ++i)
#pragma unroll
        for (int j = 0; j < 2; ++j) acc[i][j] = (f32x4){0.f, 0.f, 0.f, 0.f};

#pragma unroll
    for (int kt = 0; kt < 256; kt += 32) {
        bf16x8 ah[2], al[2], bh[2], bl[2];
#pragma unroll
        for (int s = 0; s < 2; ++s) {
            ah[s] = *(const bf16x8*)&sAhi[(wm << 5) + (s << 4) + fr][kt + fks];
            al[s] = *(const bf16x8*)&sAlo[(wm << 5) + (s << 4) + fr][kt + fks];
            bh[s] = *(const bf16x8*)&sBhi[(wn << 5) + (s << 4) + fr][kt + fks];
            bl[s] = *(const bf16x8*)&sBlo[(wn << 5) + (s << 4) + fr][kt + fks];
        }
#pragma unroll
        for (int i = 0; i < 2; ++i)
#pragma unroll
            for (int j = 0; j < 2; ++j) {
                acc[i][j] = __builtin_amdgcn_mfma_f32_16x16x32_bf16(ah[i], bh[j], acc[i][j], 0, 0, 0);
                acc[i][j] = __builtin_amdgcn_mfma_f32_16x16x32_bf16(ah[i], bl[j], acc[i][j], 0, 0, 0);
                acc[i][j] = __builtin_amdgcn_mfma_f32_16x16x32_bf16(al[i], bh[j], acc[i][j], 0, 0, 0);
            }
    }

    const int rbase = (lane >> 4) << 2;
#pragma unroll
    for (int i = 0; i < 2; ++i) {
#pragma unroll
        for (int j = 0; j < 2; ++j) {
            const int gcol = n0 + (wn << 5) + (j << 4) + fr;
            const float bias = (ACT == 2 && gcol >= 256) ? bb2[gcol - 256] : ba[gcol];
#pragma unroll
            for (int q = 0; q < 4; ++q) {
                const int grow = m0 + (wm << 5) + (i << 4) + rbase + q;
                float x = acc[i][j][q] + bias;
                if (ACT == 1)
                    x = 1.0f - 2.0f * __builtin_amdgcn_rcpf(
                                          1.0f + __builtin_amdgcn_exp2f(C2F * x));
                if (ACT == 2)
                    x = fminf(__builtin_amdgcn_exp2f(C2F * x), 1.0e4f);
                C[(size_t)grow * Nn + gcol] = x;
            }
        }
    }
}

// ---------------------------------------------------------------------------
// gemm_stage1: fused launch.
//  blocks [0,128): h1 = tanh(X @ W1^T + b1)           (64x64 tiles, 32x4 grid)
//  blocks [128,160): Wc = [Wq;Wk] @ W2 (B not transp.), bc = Asel@b2 + bias
// ---------------------------------------------------------------------------
__global__ __launch_bounds__(256) void gemm_stage1(
    const float* __restrict__ X, const float* __restrict__ W1,
    const float* __restrict__ b1, const float* __restrict__ Wq,
    const float* __restrict__ Wk, const float* __restrict__ W2,
    const float* __restrict__ b2, const float* __restrict__ bq,
    const float* __restrict__ bk, float* __restrict__ h1,
    float* __restrict__ Wc, float* __restrict__ bc) {
    __shared__ unsigned short sAhi[64][264];
    __shared__ unsigned short sAlo[64][264];
    __shared__ unsigned short sBhi[64][264];
    __shared__ unsigned short sBlo[64][264];
    __shared__ float sred[64][4];

    const int tid = threadIdx.x;
    const bool is_nt = (blockIdx.x >= 128);
    const int blk = is_nt ? (blockIdx.x - 128) : blockIdx.x;
    const int m0 = (is_nt ? (blk >> 2) : (blk >> 2)) << 6;
    const int n0 = (blk & 3) << 6;

    const int col4 = (tid & 63) << 2;
    const int rgrp = tid >> 6;

    if (!is_nt) {
        // A = X rows, B = W1 rows (both row-major, K contiguous)
        const float* Atile = X + (size_t)m0 * 256;
        const float* Wtile = W1 + (size_t)n0 * 256;
#pragma unroll
        for (int t = 0; t < 16; ++t) {
            const int row = (t << 2) + rgrp;
            f4 av = *(const f4*)&Atile[(size_t)row * 256 + col4];
            f4 wv = *(const f4*)&Wtile[(size_t)row * 256 + col4];
            split4(av, &sAhi[row][col4], &sAlo[row][col4]);
            split4(wv, &sBhi[row][col4], &sBlo[row][col4]);
        }
    } else {
        const float* Atile = (m0 < 256) ? (Wq + (size_t)m0 * 256)
                                        : (Wk + (size_t)(m0 - 256) * 256);
#pragma unroll
        for (int t = 0; t < 16; ++t) {
            const int row = (t << 2) + rgrp;
            f4 av = *(const f4*)&Atile[(size_t)row * 256 + col4];
            split4(av, &sAhi[row][col4], &sAlo[row][col4]);
        }
        // B transposed staging: sB[n][k] = W2[k][n0+n]
        const int c4 = (tid & 15) << 2;
        const int kg = tid >> 4;
#pragma unroll
        for (int t = 0; t < 16; ++t) {
            const int k = (t << 4) + kg;
            f4 wv = *(const f4*)&W2[(size_t)k * 256 + n0 + c4];
#pragma unroll
            for (int q = 0; q < 4; ++q) {
                unsigned short hi = f2bf(wv[q]);
                sBhi[c4 + q][k] = hi;
                sBlo[c4 + q][k] = f2bf(wv[q] - bf2f(hi));
            }
        }
    }
    __syncthreads();

    const int lane = tid & 63;
    const int wav = tid >> 6;
    const int wm = wav >> 1, wn = wav & 1;
    const int fr = lane & 15;
    const int fks = (lane >> 4) << 3;

    f32x4 acc[2][2];
#pragma unroll
    for (int i = 0; i < 2; ++i)
#pragma unroll
        for (int j = 0; j < 2; ++j) acc[i][j] = (f32x4){0.f, 0.f, 0.f, 0.f};

#pragma unroll
    for (int kt = 0; kt < 256; kt += 32) {
        bf16x8 ah[2], al[2], bh[2], bl[2];
#pragma unroll
        for (int s = 0; s < 2; ++s) {
            ah[s] = *(const bf16x8*)&sAhi[(wm << 5) + (s << 4) + fr][kt + fks];
            al[s] = *(const bf16x8*)&sAlo[(wm << 5) + (s << 4) + fr][kt + fks];
            bh[s] = *(const bf16x8*)&sBhi[(wn << 5) + (s << 4) + fr][kt + fks];
            bl[s] = *(const bf16x8*)&sBlo[(wn << 5) + (s << 4) + fr][kt + fks];
        }
#pragma unroll
        for (int i = 0; i < 2; ++i)
#pragma unroll
            for (int j = 0; j < 2; ++j) {
                acc[i][j] = __builtin_amdgcn_mfma_f32_16x16x32_bf16(ah[i], bh[j], acc[i][j], 0, 0, 0);
                acc[i][j] = __builtin_amdgcn_mfma_f32_16x16x32_bf16(ah[i], bl[j], acc[i][j], 0, 0, 0);
                acc[i][j] = __builtin_amdgcn_mfma_f32_16x16x32_bf16(al[i], bh[j], acc[i][j], 0, 0, 0);
            }
    }

    const int rbase = (lane >> 4) << 2;
    if (!is_nt) {
#pragma unroll
        for (int i = 0; i < 2; ++i)
#pragma unroll
            for (int j = 0; j < 2; ++j) {
                const int gcol = n0 + (wn << 5) + (j << 4) + fr;
                const float bias = b1[gcol];
#pragma unroll
                for (int q = 0; q < 4; ++q) {
                    const int grow = m0 + (wm << 5) + (i << 4) + rbase + q;
                    float x = acc[i][j][q] + bias;
                    x = 1.0f - 2.0f * __builtin_amdgcn_rcpf(
                                          1.0f + __builtin_amdgcn_exp2f(C2F * x));
                    h1[(size_t)grow * 256 + gcol] = x;
                }
            }
    } else {
#pragma unroll
        for (int i = 0; i < 2; ++i)
#pragma unroll
            for (int j = 0; j < 2; ++j) {
                const int gcol = n0 + (wn << 5) + (j << 4) + fr;
#pragma unroll
                for (int q = 0; q < 4; ++q) {
                    const int grow = m0 + (wm << 5) + (i << 4) + rbase + q;
                    Wc[(size_t)grow * 256 + gcol] = acc[i][j][q];
                }
            }
        if ((blk & 3) == 0) {
            const int rr = tid >> 2;
            const int part = (tid & 3) << 6;
            const int grow = m0 + rr;
            const float* Ar = (grow < 256) ? &Wq[(size_t)grow * 256]
                                           : &Wk[(size_t)(grow - 256) * 256];
            float s = 0.f;
#pragma unroll
            for (int e = 0; e < 64; e += 4) {
                f4 a = *(const f4*)&Ar[part + e];
                f4 bv = *(const f4*)&b2[part + e];
                s += a[0] * bv[0] + a[1] * bv[1] + a[2] * bv[2] + a[3] * bv[3];
            }
            sred[rr][tid & 3] = s;
            __syncthreads();
            if (tid < 64) {
                float bias = sred[tid][0] + sred[tid][1] + sred[tid][2] + sred[tid][3];
                const int g2 = m0 + tid;
                bias += (g2 < 256) ? bq[g2] : bk[g2 - 256];
                bc[g2] = bias;
            }
        }
    }
}

// ---------------------------------------------------------------------------
// pairwise: per (b, i-tile, j-tile, h-half) block writes
//   Ep[half][b,i,j] = sum_{h in half} v_h/(1+u_ih w_jh)
// 512 thr, 64x64 tile, 128 h per block, 4-way rcp batching.
// ---------------------------------------------------------------------------
__global__ __launch_bounds__(512, 4) void pairwise_kernel(
    const float* __restrict__ uwb, const float* __restrict__ v,
    float* __restrict__ Ep) {
    __shared__ float sU[2][64][68];
    __shared__ float sW[2][64][68];
    __shared__ float sV[128];

    const int tid = threadIdx.x;
    const int bb = blockIdx.x;       // 512 = 4b * 64 tiles * 2 halves
    const int hh = (bb & 1) << 7;
    const int tt = bb >> 1;
    const int b = tt >> 6;
    const int i0 = ((tt >> 3) & 7) << 6;
    const int j0 = (tt & 7) << 6;

    const float* ubase = uwb + (size_t)((b << 9) + i0) * 512 + hh;
    const float* wbase = uwb + (size_t)((b << 9) + j0) * 512 + 256 + hh;

    const int sr = tid >> 3;
    const int sc = (tid & 7) << 3;

    {
        f4 a0 = *(const f4*)&ubase[(size_t)sr * 512 + sc];
        f4 a1 = *(const f4*)&ubase[(size_t)sr * 512 + sc + 4];
        f4 b0 = *(const f4*)&wbase[(size_t)sr * 512 + sc];
        f4 b1 = *(const f4*)&wbase[(size_t)sr * 512 + sc + 4];
        *(f4*)&sU[0][sr][sc] = a0;
        *(f4*)&sU[0][sr][sc + 4] = a1;
        *(f4*)&sW[0][sr][sc] = b0;
        *(f4*)&sW[0][sr][sc + 4] = b1;
    }
    if (tid < 32) *(f4*)&sV[tid << 2] = *(const f4*)&v[hh + (tid << 2)];
    __syncthreads();

    const int ty = tid >> 5;   // 0..15: rows ty+16d
    const int tx = tid & 31;   // 0..31: cols tx+32e

    float acc[4][2];
#pragma unroll
    for (int d = 0; d < 4; ++d)
#pragma unroll
        for (int e = 0; e < 2; ++e) acc[d][e] = 0.f;

    const f2 one2 = (f2){1.f, 1.f};

#define COMPUTE_CHUNK(buf, vb)                                                 \
    {                                                                          \
        _Pragma("unroll 2") for (int h4 = 0; h4 < 64; h4 += 4) {               \
            f4 vv = *(const f4*)&sV[(vb) + h4];                                \
            f4 uu[4], ww[2];                                                   \
            _Pragma("unroll") for (int d = 0; d < 4; ++d)                      \
                uu[d] = *(const f4*)&sU[buf][ty + (d << 4)][h4];               \
            _Pragma("unroll") for (int e = 0; e < 2; ++e)                      \
                ww[e] = *(const f4*)&sW[buf][tx + (e << 5)][h4];               \
            _Pragma("unroll") for (int d = 0; d < 4; ++d)                      \
            _Pragma("unroll") for (int e = 0; e < 2; ++e) {                    \
                f2 u01 = (f2){uu[d][0], uu[d][1]};                             \
                f2 u23 = (f2){uu[d][2], uu[d][3]};                             \
                f2 w01 = (f2){ww[e][0], ww[e][1]};                             \
                f2 w23 = (f2){ww[e][2], ww[e][3]};                             \
                f2 A01 = __builtin_elementwise_fma(u01, w01, one2);            \
                f2 A23 = __builtin_elementwise_fma(u23, w23, one2);            \
                float m01 = A01.x * A01.y;                                     \
                float m23 = A23.x * A23.y;                                     \
                float P = m01 * m23;                                           \
                float t01 = fmaf(vv[0], A01.y, vv[1] * A01.x);                 \
                float t23 = fmaf(vv[2], A23.y, vv[3] * A23.x);                 \
                float Nm = fmaf(t01, m23, t23 * m01);                          \
                acc[d][e] = fmaf(Nm, __builtin_amdgcn_rcpf(P), acc[d][e]);     \
            }                                                                  \
        }                                                                      \
    }

    // prefetch chunk 1 into registers
    f4 pa0 = *(const f4*)&ubase[(size_t)sr * 512 + 64 + sc];
    f4 pa1 = *(const f4*)&ubase[(size_t)sr * 512 + 64 + sc + 4];
    f4 pb0 = *(const f4*)&wbase[(size_t)sr * 512 + 64 + sc];
    f4 pb1 = *(const f4*)&wbase[(size_t)sr * 512 + 64 + sc + 4];

    COMPUTE_CHUNK(0, 0)

    *(f4*)&sU[1][sr][sc] = pa0;
    *(f4*)&sU[1][sr][sc + 4] = pa1;
    *(f4*)&sW[1][sr][sc] = pb0;
    *(f4*)&sW[1][sr][sc + 4] = pb1;
    __syncthreads();

    COMPUTE_CHUNK(1, 64)
#undef COMPUTE_CHUNK

    float* ep = Ep + (size_t)(bb & 1) * 1048576 +
                (size_t)((b << 9) + i0) * 512 + j0;
#pragma unroll
    for (int d = 0; d < 4; ++d)
#pragma unroll
        for (int e = 0; e < 2; ++e)
            ep[(size_t)(ty + (d << 4)) * 512 + tx + (e << 5)] = acc[d][e];
}

// out[b,i,j] = Sv - (Ep0+Ep1)[b,i,j] - (Ep0+Ep1)[b,j,i]
__global__ __launch_bounds__(256) void sym_kernel(const float* __restrict__ Ep,
                                                  const float* __restrict__ v,
                                                  float* __restrict__ out) {
    __shared__ float t1[64][65];
    __shared__ float t2[64][65];
    __shared__ float red[4];

    const int tid = threadIdx.x;
    const int lane = tid & 63, wv = tid >> 6;

    float x = v[tid];
#pragma unroll
    for (int o = 32; o > 0; o >>= 1) x += __shfl_xor(x, o, 64);
    if (lane == 0) red[wv] = x;

    const int bb = blockIdx.x;
    const int b = bb >> 6;
    const int i0 = ((bb >> 3) & 7) << 6;
    const int j0 = (bb & 7) << 6;

    for (int idx = tid; idx < 4096; idx += 256) {
        const int r = idx >> 6, c = idx & 63;
        const size_t o1 = (size_t)((b << 9) + i0 + r) * 512 + j0 + c;
        const size_t o2 = (size_t)((b << 9) + j0 + r) * 512 + i0 + c;
        t1[r][c] = Ep[o1] + Ep[o1 + 1048576];
        t2[r][c] = Ep[o2] + Ep[o2 + 1048576];
    }
    __syncthreads();
    const float Sv = red[0] + red[1] + red[2] + red[3];
    for (int idx = tid; idx < 4096; idx += 256) {
        const int r = idx >> 6, c = idx & 63;
        out[(size_t)((b << 9) + i0 + r) * 512 + j0 + c] = Sv - (t1[r][c] + t2[c][r]);
    }
}

extern "C" void kernel_launch(void* const* d_in, const int* in_sizes, int n_in,
                              void* d_out, int out_size, void* d_ws, size_t ws_size,
                              hipStream_t stream) {
    const float* X  = (const float*)d_in[0];
    // d_in[1] = Y (unused)
    const float* W1 = (const float*)d_in[2];
    const float* b1 = (const float*)d_in[3];
    const float* W2 = (const float*)d_in[4];
    const float* b2 = (const float*)d_in[5];
    const float* Wq = (const float*)d_in[6];
    const float* bq = (const float*)d_in[7];
    const float* Wk = (const float*)d_in[8];
    const float* bk = (const float*)d_in[9];
    const float* v  = (const float*)d_in[10];
    // d_in[11] = k (unused)

    float* ws  = (float*)d_ws;
    float* h1  = ws;                 // 2048*256 = 524288 f
    float* uwb = ws + 524288;        // 2048*512 = 1048576 f
    float* Wc  = ws + 1572864;       // 512*256  = 131072 f
    float* bc  = ws + 1703936;       // 512 f
    float* Ep  = ws + 1704448;       // 2*1048576 f
    float* out = (float*)d_out;

    // fused: h1 = tanh(X@W1^T+b1)  and  Wc = [Wq;Wk]@W2, bc = [..]@b2 + bias
    gemm_stage1<<<160, 256, 0, stream>>>(X, W1, b1, Wq, Wk, W2, b2, bq, bk,
                                         h1, Wc, bc);
    // uwb[:, :256] = min(exp2(C2*Q),1e4), uwb[:, 256:] = min(exp2(C2*K),1e4)
    gemm_fullk<2><<<dim3(32, 8), 256, 0, stream>>>(h1, Wc, Wc + 65536, bc,
                                                   bc + 256, uwb, 512);
    // Ep[half][b,i,j] = sum_{h in half} v_h/(1+u w)
    pairwise_kernel<<<512, 512, 0, stream>>>(uwb, v, Ep);
    // out = Sv - (Ep0+Ep1) - (Ep0+Ep1)^T
    sym_kernel<<<256, 256, 0, stream>>>(Ep, v, out);
}